// Round 3
// baseline (515.863 us; speedup 1.0000x reference)
//
#include <hip/hip_runtime.h>

using u16 = unsigned short;
using u32 = unsigned int;
using u64 = unsigned long long;

typedef short short8 __attribute__((ext_vector_type(8)));
typedef float f32x4 __attribute__((ext_vector_type(4)));
typedef u32   u32x4 __attribute__((ext_vector_type(4)));
typedef u32   u32x2 __attribute__((ext_vector_type(2)));

#define T_STEPS 24
#define NB 4096
#define NF 1024
#define NH 256
#define NCLS 10
#define MROWS (T_STEPS * NB)   // 98304

static __device__ __forceinline__ float bf2f(u16 u) {
  union { u32 u; float f; } v; v.u = ((u32)u) << 16; return v.f;
}
static __device__ __forceinline__ u16 f2bf(float f) {  // round-to-nearest-even
  union { float f; u32 u; } v; v.f = f;
  u32 u = v.u;
  return (u16)((u + 0x7FFFu + ((u >> 16) & 1u)) >> 16);
}

// ---------------------------------------------------------------------------
// Prep: split f32 weights into hi/mid/lo bf16 planes at dst[n][{0,K,2K}+k].
// w = hi + mid + lo + O(2^-27 |w|)  -> per-term error below f32's own 2^-24.
// Runs every launch (ws is re-poisoned before each timed call).
// ---------------------------------------------------------------------------
__global__ __launch_bounds__(256) void k_prep(const float* __restrict__ W1,
                                              const float* __restrict__ W2,
                                              const float* __restrict__ W3,
                                              const float* __restrict__ Wo,
                                              u16* __restrict__ W1hl,
                                              u16* __restrict__ W2hl,
                                              u16* __restrict__ W3hl,
                                              u16* __restrict__ Wohl) {
  int blk = blockIdx.x, tid = threadIdx.x;
  const float* src; u16* dst; int K; int g;
  if (blk < 1024)      { src = W1; dst = W1hl; K = 1024; g = blk * 256 + tid; }
  else if (blk < 1280) { src = W2; dst = W2hl; K = 256;  g = (blk - 1024) * 256 + tid; }
  else if (blk < 1536) { src = W3; dst = W3hl; K = 256;  g = (blk - 1280) * 256 + tid; }
  else                 { src = Wo; dst = Wohl; K = 256;  g = (blk - 1536) * 256 + tid;
                         if (g >= NCLS * NH) return; }
  int n = g / K, k = g - n * K;
  float w = src[g];
  u16 hi = f2bf(w);
  float r1 = __fsub_rn(w, bf2f(hi));    // exact
  u16 mid = f2bf(r1);
  float r2 = __fsub_rn(r1, bf2f(mid));  // exact
  u16 lo = f2bf(r2);
  u16* d = dst + (size_t)n * 3 * K + k;
  d[0] = hi;
  d[K] = mid;
  d[2 * K] = lo;
}

// ---------------------------------------------------------------------------
// Encoder: per (b,f) neuron, 24-step constant-current LIF, v_th=1.0.
// Bit-exact vs np reference (no FMA contraction). Emits spike bits:
// bitsE[(t*NB+b)*32 + f/32] bit (f%32).
// ---------------------------------------------------------------------------
__global__ __launch_bounds__(256) void k_enc(const float* __restrict__ x,
                                             const float* __restrict__ fsp,
                                             u32* __restrict__ bitsE) {
  int g = blockIdx.x * 256 + threadIdx.x;   // g = b*1024 + f
  int b = g >> 10;
  int lane = threadIdx.x & 63;
  float c2 = __fmul_rn(2.0f, fsp[0]);
  float cur = __fmul_rn(c2, x[g]);
  float v = 0.0f;
  int wpair = ((g & 1023) >> 5) & ~1;       // even word index of this wave's 64 f's
  #pragma unroll
  for (int t = 0; t < T_STEPS; ++t) {
    v = __fadd_rn(v, __fmul_rn(0.1f, __fsub_rn(cur, v)));
    bool s = v > 1.0f;
    if (s) v = 0.0f;                        // v -= s*v
    u64 m = __ballot(s);
    if (lane == 0) {
      u32x2 w; w.x = (u32)m; w.y = (u32)(m >> 32);
      *(u32x2*)(bitsE + (size_t)(t * NB + b) * 32 + wpair) = w;
    }
  }
}

// ---------------------------------------------------------------------------
// LIF layer recurrence: per (b,h) neuron over 24 steps, input current
// c[t][b][h], v_th=0.33. Emits bits[(t*NB+b)*8 + h/32]. Per-op matches norse
// lif_feed_forward_step (spike from old state, then inject input).
// ---------------------------------------------------------------------------
__global__ __launch_bounds__(256) void k_lif(const float* __restrict__ c,
                                             u32* __restrict__ bits) {
  int b = blockIdx.x;
  int h = threadIdx.x;
  int lane = h & 63;
  int wpair = (h >> 5) & ~1;
  float v = 0.0f, ii = 0.0f;
  #pragma unroll
  for (int t = 0; t < T_STEPS; ++t) {
    float cv = c[(size_t)(t * NB + b) * NH + h];
    float vdec = __fadd_rn(v, __fmul_rn(0.1f, __fsub_rn(ii, v)));
    float idec = __fmul_rn(0.8f, ii);
    bool z = vdec > 0.33f;
    v = z ? 0.0f : vdec;
    ii = __fadd_rn(idec, cv);
    u64 m = __ballot(z);
    if (lane == 0) {
      u32x2 w; w.x = (u32)m; w.y = (u32)(m >> 32);
      *(u32x2*)(bits + (size_t)(t * NB + b) * 8 + wpair) = w;
    }
  }
}

// ---------------------------------------------------------------------------
// Bit-A split-bf16 GEMM: out[M][256] = sm * (a * (A @ (Whi+Wmid+Wlo)^T))
// A[M][KDIM] from bitmasks (values {0,1}); Whl is [256][3*KDIM] bf16 with
// hi plane at cols [0,KDIM), mid at [KDIM,2K), lo at [2K,3K). GEMM runs
// K' = 3*KDIM with A bit-words indexed j mod (KDIM/32).
// WG tile 128m x 256n, 4 waves of 64m x 128n, 16x16x32 bf16 MFMA,
// B double-buffered in LDS (40-u16 padded rows).
// ---------------------------------------------------------------------------
template <int KDIM>
__global__ __launch_bounds__(256, 2) void k_gemm(const u32* __restrict__ bits,
                                                 const u16* __restrict__ Whl,
                                                 float* __restrict__ out,
                                                 const float* __restrict__ esp,
                                                 float sm) {
  constexpr int KTOT = 3 * KDIM;
  constexpr int NCH  = KTOT / 32;           // k'-chunks of 32
  constexpr int NCHB = KDIM / 32;           // bit words per row (pow2)
  __shared__ u16 Bs[2][256 * 40];           // [256 rows][32k + 8 pad] bf16
  const int tid  = threadIdx.x;
  const int wid  = tid >> 6;
  const int lane = tid & 63;
  const int r0   = blockIdx.x * 128;
  const int moff = (wid & 1) * 64;
  const int noff = (wid >> 1) * 128;

  const float a = esp ? __fmul_rn(5.0f, esp[0]) : 1.0f;

  // --- staging: thread t loads row n = r*64 + t/4, 16B at (t%4)*16 per chunk
  const int srow  = tid >> 2;
  const int selem = (tid & 3) * 8;
  u32x4 stg[4];
  const u16* Wbase = Whl + (size_t)srow * KTOT + selem;
  auto load_stage = [&](int j) {
    #pragma unroll
    for (int r = 0; r < 4; ++r)
      stg[r] = *(const u32x4*)(Wbase + (size_t)r * 64 * KTOT + j * 32);
  };
  auto write_stage = [&](int buf) {
    u16* base = &Bs[buf][(size_t)srow * 40 + selem];
    #pragma unroll
    for (int r = 0; r < 4; ++r)
      *(u32x4*)(base + r * 64 * 40) = stg[r];
  };

  // --- A bitmask rows for this wave's 4 m-subtiles
  const u32* brow[4];
  #pragma unroll
  for (int ms = 0; ms < 4; ++ms)
    brow[ms] = bits + (size_t)(r0 + moff + ms * 16 + (lane & 15)) * NCHB;
  const int bsh = (lane >> 4) * 8;

  f32x4 acc[4][8];
  #pragma unroll
  for (int ms = 0; ms < 4; ++ms)
    #pragma unroll
    for (int ns = 0; ns < 8; ++ns)
      #pragma unroll
      for (int i = 0; i < 4; ++i) acc[ms][ns][i] = 0.0f;

  load_stage(0);
  u32 bw[4];
  #pragma unroll
  for (int ms = 0; ms < 4; ++ms) bw[ms] = brow[ms][0];

  const u32 av = 0x3F80u;  // bf16 1.0
  #pragma unroll 2
  for (int j = 0; j < NCH; ++j) {
    write_stage(j & 1);
    if (j + 1 < NCH) load_stage(j + 1);
    __syncthreads();

    // A fragments from bits: 8 bits -> 8 bf16 {0,1}, pair-packed via mul trick
    short8 afr[4];
    #pragma unroll
    for (int ms = 0; ms < 4; ++ms) {
      u32 by = (bw[ms] >> bsh) & 0xFFu;
      u32x4 d;
      d.x = ((by & 1u)        | ((by & 2u)        << 15)) * av;
      d.y = (((by >> 2) & 1u) | (((by >> 2) & 2u) << 15)) * av;
      d.z = (((by >> 4) & 1u) | (((by >> 4) & 2u) << 15)) * av;
      d.w = (((by >> 6) & 1u) | (((by >> 6) & 2u) << 15)) * av;
      afr[ms] = __builtin_bit_cast(short8, d);
    }
    if (j + 1 < NCH) {
      const int wn = (j + 1) & (NCHB - 1);  // j mod KDIM/32
      #pragma unroll
      for (int ms = 0; ms < 4; ++ms) bw[ms] = brow[ms][wn];
    }

    short8 bfr[8];
    const u16* bs = &Bs[j & 1][0];
    #pragma unroll
    for (int ns = 0; ns < 8; ++ns) {
      int nrow = noff + ns * 16 + (lane & 15);
      bfr[ns] = *(const short8*)(bs + (size_t)nrow * 40 + (lane >> 4) * 8);
    }
    #pragma unroll
    for (int ms = 0; ms < 4; ++ms)
      #pragma unroll
      for (int ns = 0; ns < 8; ++ns)
        acc[ms][ns] = __builtin_amdgcn_mfma_f32_16x16x32_bf16(afr[ms], bfr[ns],
                                                              acc[ms][ns], 0, 0, 0);
  }

  // epilogue: C/D layout col = lane&15, row = (lane>>4)*4 + i
  #pragma unroll
  for (int ms = 0; ms < 4; ++ms) {
    const int row = r0 + moff + ms * 16 + (lane >> 4) * 4;
    #pragma unroll
    for (int ns = 0; ns < 8; ++ns) {
      const int col = noff + ns * 16 + (lane & 15);
      float* op = out + (size_t)row * NH + col;
      #pragma unroll
      for (int i = 0; i < 4; ++i)
        op[(size_t)i * NH] = __fmul_rn(sm, __fmul_rn(a, acc[ms][ns][i]));
    }
  }
}

// ---------------------------------------------------------------------------
// Readout GEMM: cout[M][10] = zbits @ (Wohi+Womid+Wolo)^T, Wohl [10][768] bf16.
// ---------------------------------------------------------------------------
__global__ __launch_bounds__(256) void k_gout(const u32* __restrict__ bits,
                                              const u16* __restrict__ Wohl,
                                              float* __restrict__ out) {
  const int tid  = threadIdx.x;
  const int wid  = tid >> 6;
  const int lane = tid & 63;
  const int r0   = (blockIdx.x * 4 + wid) * 16;
  const u32* brow = bits + (size_t)(r0 + (lane & 15)) * 8;
  const int bsh = (lane >> 4) * 8;
  const int n = lane & 15;
  const u32 av = 0x3F80u;
  f32x4 acc;
  #pragma unroll
  for (int i = 0; i < 4; ++i) acc[i] = 0.0f;
  #pragma unroll
  for (int j = 0; j < 24; ++j) {            // K' = 768
    u32 by = (brow[j & 7] >> bsh) & 0xFFu;
    u32x4 d;
    d.x = ((by & 1u)        | ((by & 2u)        << 15)) * av;
    d.y = (((by >> 2) & 1u) | (((by >> 2) & 2u) << 15)) * av;
    d.z = (((by >> 4) & 1u) | (((by >> 4) & 2u) << 15)) * av;
    d.w = (((by >> 6) & 1u) | (((by >> 6) & 2u) << 15)) * av;
    short8 afr = __builtin_bit_cast(short8, d);
    short8 bfr;
    #pragma unroll
    for (int q = 0; q < 8; ++q) bfr[q] = 0;
    if (n < NCLS)
      bfr = *(const short8*)(Wohl + (size_t)n * 768 + j * 32 + (lane >> 4) * 8);
    acc = __builtin_amdgcn_mfma_f32_16x16x32_bf16(afr, bfr, acc, 0, 0, 0);
  }
  if (n < NCLS) {
    const int row = r0 + (lane >> 4) * 4;
    #pragma unroll
    for (int i = 0; i < 4; ++i)
      out[(size_t)(row + i) * NCLS + n] = acc[i];
  }
}

// ---------------------------------------------------------------------------
// Leaky-integrator readout over 24 steps; final v_li -> f32 output [4096,10]
// ---------------------------------------------------------------------------
__global__ __launch_bounds__(256) void k_read(const float* __restrict__ cin,
                                              float* __restrict__ outp) {
  int g = blockIdx.x * 256 + threadIdx.x;   // 40960 = 4096*10
  int b = g / NCLS, cls = g - b * NCLS;
  float v = 0.0f, ii = 0.0f;
  #pragma unroll
  for (int t = 0; t < T_STEPS; ++t) {
    v = __fadd_rn(v, __fmul_rn(0.1f, __fsub_rn(ii, v)));   // uses OLD i_li
    ii = __fadd_rn(__fmul_rn(0.8f, ii), cin[(size_t)(t * NB + b) * NCLS + cls]);
  }
  outp[g] = v;
}

// ---------------------------------------------------------------------------
extern "C" void kernel_launch(void* const* d_in, const int* in_sizes, int n_in,
                              void* d_out, int out_size, void* d_ws, size_t ws_size,
                              hipStream_t stream) {
  const float* x  = (const float*)d_in[0];
  const float* W1 = (const float*)d_in[1];
  const float* W2 = (const float*)d_in[2];
  const float* W3 = (const float*)d_in[3];
  const float* Wo = (const float*)d_in[4];
  const float* fs = (const float*)d_in[5];
  const float* es = (const float*)d_in[6];

  char* ws = (char*)d_ws;
  const size_t off_bitsE  = 0;                                    // 12.58 MB
  const size_t off_bitsZ1 = off_bitsE  + (size_t)MROWS * 32 * 4;
  const size_t off_bitsZ2 = off_bitsZ1 + (size_t)MROWS * 8 * 4;   // 3.15 MB each
  const size_t off_c      = off_bitsZ2 + (size_t)MROWS * 8 * 4;   // 100.7 MB (reused 3x)
  const size_t off_cout   = off_c      + (size_t)MROWS * NH * 4;  // 3.93 MB
  const size_t off_wohl   = off_cout   + (size_t)MROWS * NCLS * 4;
  const size_t need       = off_wohl   + (size_t)NCLS * 3 * NH * 2;
  if (ws_size < need) return;  // fail loudly (zero output) rather than fault

  u32*   bitsE  = (u32*)(ws + off_bitsE);
  u32*   bitsZ1 = (u32*)(ws + off_bitsZ1);
  u32*   bitsZ2 = (u32*)(ws + off_bitsZ2);
  float* cbuf   = (float*)(ws + off_c);
  float* coutb  = (float*)(ws + off_cout);
  // W1/W2/W3 split planes live INSIDE the cout region (dead before k_gout
  // writes cout: 1.5 + 0.375 + 0.375 = 2.25 MB < 3.93 MB). Wohl lives past
  // cout (read during k_gout).
  u16* W1hl = (u16*)(ws + off_cout);                              // 1.5 MB
  u16* W2hl = (u16*)(ws + off_cout + (size_t)NH * 3 * NF * 2);    // 0.375 MB
  u16* W3hl = (u16*)(ws + off_cout + (size_t)NH * 3 * NF * 2 + (size_t)NH * 3 * NH * 2);
  u16* Wohl = (u16*)(ws + off_wohl);                              // 15 KB

  // split weights into hi/mid/lo bf16 planes
  k_prep<<<dim3(1546), dim3(256), 0, stream>>>(W1, W2, W3, Wo, W1hl, W2hl, W3hl, Wohl);
  // encoder spikes for all 24 steps (bit-exact vs np)
  k_enc<<<dim3((NB * NF) / 256), dim3(256), 0, stream>>>(x, fs, bitsE);
  // layer 1 currents: c = 1.2 * ((5*es*s) @ W1^T), all t at once
  k_gemm<NF><<<dim3(MROWS / 128), dim3(256), 0, stream>>>(bitsE, W1hl, cbuf, es, 1.2f);
  k_lif<<<dim3(NB), dim3(256), 0, stream>>>(cbuf, bitsZ1);
  // layer 2
  k_gemm<NH><<<dim3(MROWS / 128), dim3(256), 0, stream>>>(bitsZ1, W2hl, cbuf, nullptr, 1.2f);
  k_lif<<<dim3(NB), dim3(256), 0, stream>>>(cbuf, bitsZ2);
  // layer 3
  k_gemm<NH><<<dim3(MROWS / 128), dim3(256), 0, stream>>>(bitsZ2, W3hl, cbuf, nullptr, 1.2f);
  k_lif<<<dim3(NB), dim3(256), 0, stream>>>(cbuf, bitsZ1);   // z3 bits (reuse)
  // readout projection + leaky-integrator decode
  k_gout<<<dim3(MROWS / 64), dim3(256), 0, stream>>>(bitsZ1, Wohl, coutb);
  k_read<<<dim3((NB * NCLS) / 256), dim3(256), 0, stream>>>(coutb, (float*)d_out);
}

// Round 4
// 359.797 us; speedup vs baseline: 1.4338x; 1.4338x over previous
//
#include <hip/hip_runtime.h>

using u16 = unsigned short;
using u32 = unsigned int;
using u64 = unsigned long long;

typedef short  short8 __attribute__((ext_vector_type(8)));
typedef _Float16 half8 __attribute__((ext_vector_type(8)));
typedef float  f32x4 __attribute__((ext_vector_type(4)));
typedef u32    u32x4 __attribute__((ext_vector_type(4)));
typedef u32    u32x2 __attribute__((ext_vector_type(2)));

#define T_STEPS 24
#define NB 4096
#define NF 1024
#define NH 256
#define NCLS 10
#define MROWS (T_STEPS * NB)   // 98304

static __device__ __forceinline__ u16 f16bits(float f) {
  _Float16 h = (_Float16)f;
  return __builtin_bit_cast(u16, h);
}

// ---------------------------------------------------------------------------
// Prep: split f32 weights into hi/lo f16 planes at dst[n][k], dst[n][K+k].
// w = hi + 2^-12 * lo  (lo stored pre-scaled by 2^12; hi subnormals squashed
// so residual goes to lo). Per-term error ~2^-23|w| (f32-class).
// ---------------------------------------------------------------------------
__global__ __launch_bounds__(256) void k_prep(const float* __restrict__ W1,
                                              const float* __restrict__ W2,
                                              const float* __restrict__ W3,
                                              const float* __restrict__ Wo,
                                              u16* __restrict__ W1hl,
                                              u16* __restrict__ W2hl,
                                              u16* __restrict__ W3hl,
                                              u16* __restrict__ Wohl) {
  int blk = blockIdx.x, tid = threadIdx.x;
  const float* src; u16* dst; int K; int g;
  if (blk < 1024)      { src = W1; dst = W1hl; K = 1024; g = blk * 256 + tid; }
  else if (blk < 1280) { src = W2; dst = W2hl; K = 256;  g = (blk - 1024) * 256 + tid; }
  else if (blk < 1536) { src = W3; dst = W3hl; K = 256;  g = (blk - 1280) * 256 + tid; }
  else                 { src = Wo; dst = Wohl; K = 256;  g = (blk - 1536) * 256 + tid;
                         if (g >= NCLS * NH) return; }
  int n = g / K, k = g - n * K;
  float w = src[g];
  _Float16 h = (_Float16)w;
  float hf = (float)h;
  if (__builtin_fabsf(hf) < 6.103515625e-05f) { h = (_Float16)0.0f; hf = 0.0f; }
  float r = __fmul_rn(__fsub_rn(w, hf), 4096.0f);   // exact residual * 2^12
  _Float16 lo = (_Float16)r;
  u16* d = dst + (size_t)n * 2 * K + k;
  d[0] = __builtin_bit_cast(u16, h);
  d[K] = __builtin_bit_cast(u16, lo);
}

// ---------------------------------------------------------------------------
// Encoder: per (b,f) neuron, 24-step constant-current LIF, v_th=1.0.
// Bit-exact vs np reference. bitsE[(t*NB+b)*32 + f/32] bit (f%32).
// ---------------------------------------------------------------------------
__global__ __launch_bounds__(256) void k_enc(const float* __restrict__ x,
                                             const float* __restrict__ fsp,
                                             u32* __restrict__ bitsE) {
  int g = blockIdx.x * 256 + threadIdx.x;   // g = b*1024 + f
  int b = g >> 10;
  int lane = threadIdx.x & 63;
  float c2 = __fmul_rn(2.0f, fsp[0]);
  float cur = __fmul_rn(c2, x[g]);
  float v = 0.0f;
  int wpair = ((g & 1023) >> 5) & ~1;
  #pragma unroll
  for (int t = 0; t < T_STEPS; ++t) {
    v = __fadd_rn(v, __fmul_rn(0.1f, __fsub_rn(cur, v)));
    bool s = v > 1.0f;
    if (s) v = 0.0f;
    u64 m = __ballot(s);
    if (lane == 0) {
      u32x2 w; w.x = (u32)m; w.y = (u32)(m >> 32);
      *(u32x2*)(bitsE + (size_t)(t * NB + b) * 32 + wpair) = w;
    }
  }
}

// ---------------------------------------------------------------------------
// LIF layer recurrence over 24 steps, v_th=0.33; bits[(t*NB+b)*8 + h/32].
// ---------------------------------------------------------------------------
__global__ __launch_bounds__(256) void k_lif(const float* __restrict__ c,
                                             u32* __restrict__ bits) {
  int b = blockIdx.x;
  int h = threadIdx.x;
  int lane = h & 63;
  int wpair = (h >> 5) & ~1;
  float v = 0.0f, ii = 0.0f;
  #pragma unroll
  for (int t = 0; t < T_STEPS; ++t) {
    float cv = c[(size_t)(t * NB + b) * NH + h];
    float vdec = __fadd_rn(v, __fmul_rn(0.1f, __fsub_rn(ii, v)));
    float idec = __fmul_rn(0.8f, ii);
    bool z = vdec > 0.33f;
    v = z ? 0.0f : vdec;
    ii = __fadd_rn(idec, cv);
    u64 m = __ballot(z);
    if (lane == 0) {
      u32x2 w; w.x = (u32)m; w.y = (u32)(m >> 32);
      *(u32x2*)(bits + (size_t)(t * NB + b) * 8 + wpair) = w;
    }
  }
}

// ---------------------------------------------------------------------------
// Bit-A split-f16 GEMM: out[M][256] = sm * a * (A @ (Whi + 2^-12*Wlo)^T)
// A from bitmasks; amplitude {1.0, 2^-12} applied on the A side per k-half.
// Whl [256][2*KDIM] f16 (hi | lo*2^12). WG 128m x 256n, 4 waves 64m x 128n,
// 16x16x32 f16 MFMA. Staging: global_load_lds width=16 into 64B-row LDS
// with source-side XOR-16B-unit swizzle (reads land 2 lanes/bank = free).
// K-loop: 64-k super-chunks, double-buffered, ONE barrier per super-chunk
// placed BEFORE the next stage issue (vmcnt drain = exactly current buffer).
// ---------------------------------------------------------------------------
template <int KDIM>
__global__ __launch_bounds__(256, 2) void k_gemm(const u32* __restrict__ bits,
                                                 const u16* __restrict__ Whl,
                                                 float* __restrict__ out,
                                                 const float* __restrict__ esp,
                                                 float sm) {
  constexpr int KTOT  = 2 * KDIM;
  constexpr int NSC   = KTOT / 64;     // super-chunks of 64 k
  constexpr int NCHB  = KDIM / 32;     // bit words per row
  constexpr int NPAIR = NCHB / 2;      // u32x2 per row (pow2)
  __shared__ __align__(16) u16 Bs[2 * 16384];   // 2 x 32KB: 256 rows x 64B, swizzled
  const int tid  = threadIdx.x;
  const int wid  = tid >> 6;
  const int lane = tid & 63;
  const int r0   = blockIdx.x * 128;
  const int moff = (wid & 1) * 64;
  const int noff = (wid >> 1) * 128;

  const float a = esp ? __fmul_rn(5.0f, esp[0]) : 1.0f;

  // --- staging source: lane covers global row wid*64 + r*8 + (lane>>3),
  //     16B unit (lane&7)^(lane>>3) of the current 128B k-slab (XOR swizzle)
  const int swz16 = ((lane & 7) ^ (lane >> 3)) * 16;
  const char* gstage = (const char*)Whl +
      (size_t)(wid * 64 + (lane >> 3)) * (KTOT * 2) + swz16;
  const int ldsw = wid * 4096;   // u16 units: wave-uniform dest base

  auto stage = [&](int s, int b) {
    const char* g = gstage + (size_t)s * 128;
    #pragma unroll
    for (int r = 0; r < 8; ++r)
      __builtin_amdgcn_global_load_lds(
          (const __attribute__((address_space(1))) u32*)(g + (size_t)r * (8 * KTOT * 2)),
          (__attribute__((address_space(3))) u32*)&Bs[b * 16384 + ldsw + r * 512],
          16, 0, 0);
  };

  // --- A bit rows (u32x2 = both 32-k halves of a super-chunk)
  const u32x2* bp[4];
  #pragma unroll
  for (int ms = 0; ms < 4; ++ms)
    bp[ms] = (const u32x2*)(bits + (size_t)(r0 + moff + ms * 16 + (lane & 15)) * NCHB);

  const int bsh = (lane >> 4) * 8;
  auto expand = [&](u32 word, u32 av) -> half8 {
    u32 by = (word >> bsh) & 0xFFu;
    u32 sp = by * 0x8001u;             // bit k at positions k and k+15
    u32x4 d;
    d.x = (sp & 0x10001u) * av;
    d.y = ((sp >> 2) & 0x10001u) * av;
    d.z = ((sp >> 4) & 0x10001u) * av;
    d.w = ((sp >> 6) & 0x10001u) * av;
    return __builtin_bit_cast(half8, d);
  };

  // --- B-frag per-lane read bases (swizzled), h = 0/1 k-half
  const int rbase = (noff + (lane & 15)) * 64;  // u16 units
  int pu8[2];
  #pragma unroll
  for (int h = 0; h < 2; ++h)
    pu8[h] = (((4 * h + (lane >> 4)) ^ (lane & 7)) * 8);

  f32x4 acc[4][8];
  #pragma unroll
  for (int ms = 0; ms < 4; ++ms)
    #pragma unroll
    for (int ns = 0; ns < 8; ++ns)
      #pragma unroll
      for (int i = 0; i < 4; ++i) acc[ms][ns][i] = 0.0f;

  stage(0, 0);
  u32x2 bw[4];
  #pragma unroll
  for (int ms = 0; ms < 4; ++ms) bw[ms] = bp[ms][0];

  #pragma unroll 2
  for (int s = 0; s < NSC; ++s) {
    __syncthreads();   // drains vmcnt: buf[s&1] ready; prior readers of other buf done
    if (s + 1 < NSC) stage(s + 1, (s + 1) & 1);

    u32x2 nb[4];
    if (s + 1 < NSC) {
      const int pi = (s + 1) & (NPAIR - 1);
      #pragma unroll
      for (int ms = 0; ms < 4; ++ms) nb[ms] = bp[ms][pi];
    }

    const u32 av = (s < NSC / 2) ? 0x3C00u : 0x0C00u;   // f16 1.0 / 2^-12
    half8 afr[4][2];
    #pragma unroll
    for (int ms = 0; ms < 4; ++ms) {
      afr[ms][0] = expand(bw[ms].x, av);
      afr[ms][1] = expand(bw[ms].y, av);
    }

    const int bufo = (s & 1) * 16384;
    #pragma unroll
    for (int h = 0; h < 2; ++h) {
      #pragma unroll
      for (int ns = 0; ns < 8; ++ns) {
        half8 bfr = *(const half8*)&Bs[bufo + rbase + ns * 1024 + pu8[h]];
        #pragma unroll
        for (int ms = 0; ms < 4; ++ms)
          acc[ms][ns] = __builtin_amdgcn_mfma_f32_16x16x32_f16(afr[ms][h], bfr,
                                                               acc[ms][ns], 0, 0, 0);
      }
    }
    if (s + 1 < NSC) {
      #pragma unroll
      for (int ms = 0; ms < 4; ++ms) bw[ms] = nb[ms];
    }
  }

  // epilogue: C/D layout col = lane&15, row = (lane>>4)*4 + i  (verified R3)
  #pragma unroll
  for (int ms = 0; ms < 4; ++ms) {
    const int row = r0 + moff + ms * 16 + (lane >> 4) * 4;
    #pragma unroll
    for (int ns = 0; ns < 8; ++ns) {
      const int col = noff + ns * 16 + (lane & 15);
      float* op = out + (size_t)row * NH + col;
      #pragma unroll
      for (int i = 0; i < 4; ++i)
        op[(size_t)i * NH] = __fmul_rn(sm, __fmul_rn(a, acc[ms][ns][i]));
    }
  }
}

// ---------------------------------------------------------------------------
// Readout GEMM: cout[M][10] = zbits @ (Wohi + 2^-12*Wolo)^T, Wohl [10][512] f16
// ---------------------------------------------------------------------------
__global__ __launch_bounds__(256) void k_gout(const u32* __restrict__ bits,
                                              const u16* __restrict__ Wohl,
                                              float* __restrict__ out) {
  const int tid  = threadIdx.x;
  const int wid  = tid >> 6;
  const int lane = tid & 63;
  const int r0   = (blockIdx.x * 4 + wid) * 16;
  const u32* brow = bits + (size_t)(r0 + (lane & 15)) * 8;
  const int bsh = (lane >> 4) * 8;
  const int n = lane & 15;
  f32x4 acc;
  #pragma unroll
  for (int i = 0; i < 4; ++i) acc[i] = 0.0f;
  #pragma unroll
  for (int j = 0; j < 16; ++j) {            // K' = 512
    const u32 av = (j < 8) ? 0x3C00u : 0x0C00u;
    u32 by = (brow[j & 7] >> bsh) & 0xFFu;
    u32 sp = by * 0x8001u;
    u32x4 d;
    d.x = (sp & 0x10001u) * av;
    d.y = ((sp >> 2) & 0x10001u) * av;
    d.z = ((sp >> 4) & 0x10001u) * av;
    d.w = ((sp >> 6) & 0x10001u) * av;
    half8 afr = __builtin_bit_cast(half8, d);
    half8 bfr;
    #pragma unroll
    for (int q = 0; q < 8; ++q) bfr[q] = (_Float16)0.0f;
    if (n < NCLS)
      bfr = *(const half8*)(Wohl + (size_t)n * 512 + j * 32 + (lane >> 4) * 8);
    acc = __builtin_amdgcn_mfma_f32_16x16x32_f16(afr, bfr, acc, 0, 0, 0);
  }
  if (n < NCLS) {
    const int row = r0 + (lane >> 4) * 4;
    #pragma unroll
    for (int i = 0; i < 4; ++i)
      out[(size_t)(row + i) * NCLS + n] = acc[i];
  }
}

// ---------------------------------------------------------------------------
// Leaky-integrator readout over 24 steps; final v_li -> f32 output [4096,10]
// ---------------------------------------------------------------------------
__global__ __launch_bounds__(256) void k_read(const float* __restrict__ cin,
                                              float* __restrict__ outp) {
  int g = blockIdx.x * 256 + threadIdx.x;   // 40960
  int b = g / NCLS, cls = g - b * NCLS;
  float v = 0.0f, ii = 0.0f;
  #pragma unroll
  for (int t = 0; t < T_STEPS; ++t) {
    v = __fadd_rn(v, __fmul_rn(0.1f, __fsub_rn(ii, v)));
    ii = __fadd_rn(__fmul_rn(0.8f, ii), cin[(size_t)(t * NB + b) * NCLS + cls]);
  }
  outp[g] = v;
}

// ---------------------------------------------------------------------------
extern "C" void kernel_launch(void* const* d_in, const int* in_sizes, int n_in,
                              void* d_out, int out_size, void* d_ws, size_t ws_size,
                              hipStream_t stream) {
  const float* x  = (const float*)d_in[0];
  const float* W1 = (const float*)d_in[1];
  const float* W2 = (const float*)d_in[2];
  const float* W3 = (const float*)d_in[3];
  const float* Wo = (const float*)d_in[4];
  const float* fs = (const float*)d_in[5];
  const float* es = (const float*)d_in[6];

  char* ws = (char*)d_ws;
  const size_t off_bitsE  = 0;                                    // 12.58 MB
  const size_t off_bitsZ1 = off_bitsE  + (size_t)MROWS * 32 * 4;
  const size_t off_bitsZ2 = off_bitsZ1 + (size_t)MROWS * 8 * 4;   // 3.15 MB each
  const size_t off_c      = off_bitsZ2 + (size_t)MROWS * 8 * 4;   // 100.7 MB
  const size_t off_cout   = off_c      + (size_t)MROWS * NH * 4;  // 3.93 MB
  const size_t off_wohl   = off_cout   + (size_t)MROWS * NCLS * 4;
  const size_t need       = off_wohl   + (size_t)NCLS * 2 * NH * 2;
  if (ws_size < need) return;

  u32*   bitsE  = (u32*)(ws + off_bitsE);
  u32*   bitsZ1 = (u32*)(ws + off_bitsZ1);
  u32*   bitsZ2 = (u32*)(ws + off_bitsZ2);
  float* cbuf   = (float*)(ws + off_c);
  float* coutb  = (float*)(ws + off_cout);
  // W planes live inside the cout region (1.0+0.25+0.25 MB < 3.93 MB, dead
  // before k_gout writes cout); Wohl lives past cout.
  u16* W1hl = (u16*)(ws + off_cout);                              // 1.0 MB
  u16* W2hl = (u16*)(ws + off_cout + (size_t)NH * 2 * NF * 2);    // 0.25 MB
  u16* W3hl = (u16*)(ws + off_cout + (size_t)NH * 2 * NF * 2 + (size_t)NH * 2 * NH * 2);
  u16* Wohl = (u16*)(ws + off_wohl);                              // 10 KB

  k_prep<<<dim3(1546), dim3(256), 0, stream>>>(W1, W2, W3, Wo, W1hl, W2hl, W3hl, Wohl);
  k_enc<<<dim3((NB * NF) / 256), dim3(256), 0, stream>>>(x, fs, bitsE);
  k_gemm<NF><<<dim3(MROWS / 128), dim3(256), 0, stream>>>(bitsE, W1hl, cbuf, es, 1.2f);
  k_lif<<<dim3(NB), dim3(256), 0, stream>>>(cbuf, bitsZ1);
  k_gemm<NH><<<dim3(MROWS / 128), dim3(256), 0, stream>>>(bitsZ1, W2hl, cbuf, nullptr, 1.2f);
  k_lif<<<dim3(NB), dim3(256), 0, stream>>>(cbuf, bitsZ2);
  k_gemm<NH><<<dim3(MROWS / 128), dim3(256), 0, stream>>>(bitsZ2, W3hl, cbuf, nullptr, 1.2f);
  k_lif<<<dim3(NB), dim3(256), 0, stream>>>(cbuf, bitsZ1);
  k_gout<<<dim3(MROWS / 64), dim3(256), 0, stream>>>(bitsZ1, Wohl, coutb);
  k_read<<<dim3((NB * NCLS) / 256), dim3(256), 0, stream>>>(coutb, (float*)d_out);
}